// Round 5
// baseline (86.988 us; speedup 1.0000x reference)
//
#include <hip/hip_runtime.h>
#include <math.h>

#define NB   16384
#define SEQ  10
#define DIM  8
#define TRIL 36

__device__ __forceinline__ constexpr int tri(int r, int c) { return r * (r + 1) / 2 + c; } // r >= c

// ---- intra-octet cross-lane: DPP quad perms (1-cycle VALU) + ds_swizzle xor masks ----
template <int CTRL>
__device__ __forceinline__ float fperm(float v) {
    return __int_as_float(__builtin_amdgcn_mov_dpp(__float_as_int(v), CTRL, 0xf, 0xf, true));
}
template <int CTRL>
__device__ __forceinline__ double dperm(double v) {
    long long u = __double_as_longlong(v);
    int lo = (int)(u & 0xffffffffLL);
    int hi = (int)(((unsigned long long)u) >> 32);
    lo = __builtin_amdgcn_mov_dpp(lo, CTRL, 0xf, 0xf, true);
    hi = __builtin_amdgcn_mov_dpp(hi, CTRL, 0xf, 0xf, true);
    return __longlong_as_double(((long long)hi << 32) | (long long)(unsigned)lo);
}
// quad perms: xor1=0xB1 [1,0,3,2], xor2=0x4E [2,3,0,1], xor3=0x1B [3,2,1,0]
// ds_swizzle BitMode offset=(xor<<10)|(or<<5)|and ; xor-M within 32-lane group, and=0x1F
__device__ __forceinline__ float fswz4(float v) {
    return __int_as_float(__builtin_amdgcn_ds_swizzle(__float_as_int(v), 0x101F));
}
__device__ __forceinline__ double dswz4(double v) {
    long long u = __double_as_longlong(v);
    int lo = (int)(u & 0xffffffffLL);
    int hi = (int)(((unsigned long long)u) >> 32);
    lo = __builtin_amdgcn_ds_swizzle(lo, 0x101F);
    hi = __builtin_amdgcn_ds_swizzle(hi, 0x101F);
    return __longlong_as_double(((long long)hi << 32) | (long long)(unsigned)lo);
}

// ---- fp64 rsqrt/rcp via HW seed + Newton ----
__device__ __forceinline__ double fast_rsqrt(double x) {
    double r = __builtin_amdgcn_rsq(x);
    r = r * (1.5 - 0.5 * x * r * r);
    r = r * (1.5 - 0.5 * x * r * r);
    return r;
}
__device__ __forceinline__ double fast_rcp(double x) {
    double r = __builtin_amdgcn_rcp(x);
    r = r * (2.0 - x * r);
    r = r * (2.0 - x * r);
    return r;
}
__device__ __forceinline__ double fast_sqrt(double x) { return x * fast_rsqrt(x); }

// 144B embedding row = 9 aligned float4
__device__ __forceinline__ void load_row(const float* __restrict__ emb, int tok, float (&F)[TRIL]) {
    const float4* q = (const float4*)(emb + (size_t)tok * TRIL);
    #pragma unroll
    for (int i = 0; i < 9; ++i) {
        float4 v = q[i];
        F[4*i+0] = v.x; F[4*i+1] = v.y; F[4*i+2] = v.z; F[4*i+3] = v.w;
    }
}

// density = (L L^T + 2e-6 I) / (||L||_F^2 + 1.6e-5 + 1e-6), diag(L) clamped >= 1e-4 in fp32.
// fp64 products/sums: density errors perturb eigenvalues ABSOLUTELY (500x amplified at small
// lambda through sqrt(lambda+1e-6)), so this stage stays fp64.
template <bool ACCUM>
__device__ __forceinline__ void density_from(float (&Lf)[TRIL], double (&dst)[TRIL]) {
    #pragma unroll
    for (int d = 0; d < DIM; ++d) Lf[tri(d, d)] = fmaxf(Lf[tri(d, d)], 1.0e-4f);
    double tr = 1.6e-5;
    #pragma unroll
    for (int i = 0; i < TRIL; ++i) { double v = (double)Lf[i]; tr += v * v; }
    double inv = fast_rcp(tr + 1.0e-6);
    #pragma unroll
    for (int i = 0; i < DIM; ++i) {
        #pragma unroll
        for (int j = 0; j <= i; ++j) {
            double sum = (i == j) ? 2.0e-6 : 0.0;
            #pragma unroll
            for (int k = 0; k <= j; ++k) sum += (double)Lf[tri(i, k)] * (double)Lf[tri(j, k)];
            if (ACCUM) dst[tri(i, j)] += sum * inv;
            else       dst[tri(i, j)]  = sum * inv;
        }
    }
}

// in-place fp64 Cholesky (lower-sym 36)
__device__ __forceinline__ void chol36(double (&M)[TRIL]) {
    #pragma unroll
    for (int j = 0; j < DIM; ++j) {
        double d = M[tri(j, j)];
        #pragma unroll
        for (int k = 0; k < j; ++k) d -= M[tri(j, k)] * M[tri(j, k)];
        d = fmax(d, 1.0e-30);
        double invd = fast_rsqrt(d);
        M[tri(j, j)] = d * invd;
        #pragma unroll
        for (int i = j + 1; i < DIM; ++i) {
            double v = M[tri(i, j)];
            #pragma unroll
            for (int k = 0; k < j; ++k) v -= M[tri(i, k)] * M[tri(j, k)];
            M[tri(i, j)] = v * invd;
        }
    }
}

// one XOR-pairing Jacobi round: partner = lane ^ M. tau computed from local view gives
// exactly opposite s / identical c on the two partners => symmetric update own'=c*own-s*recv.
template <int M>
__device__ __forceinline__ float jrecv(float v) {
    if constexpr (M == 1) return fperm<0xB1>(v);
    else if constexpr (M == 2) return fperm<0x4E>(v);
    else if constexpr (M == 3) return fperm<0x1B>(v);
    else return __int_as_float(__builtin_amdgcn_ds_swizzle(__float_as_int(v), (M << 10) | 0x1F));
}
template <int M>
__device__ __forceinline__ void jround(float (&o)[DIM], bool& conv) {
    float r[DIM];
    #pragma unroll
    for (int k = 0; k < DIM; ++k) r[k] = jrecv<M>(o[k]);
    float xo = 0.0f, xr = 0.0f, z = 0.0f;
    #pragma unroll
    for (int k = 0; k < DIM; ++k) {
        xo = fmaf(o[k], o[k], xo);
        xr = fmaf(r[k], r[k], xr);
        z  = fmaf(o[k], r[k], z);
    }
    float z2 = z * z;
    float d  = xr - xo;
    if (z2 > 1.0e-12f * xo * xr && z2 > 1.0e-12f * d * d) conv = false;
    if (z2 > 1.0e-16f * xo * xr) {   // skip pure-noise rotations; guards rcp(0)
        float tau = d * (0.5f * __builtin_amdgcn_rcpf(z));
        float t = __builtin_amdgcn_rcpf(fabsf(tau) + sqrtf(fmaf(tau, tau, 1.0f)));
        t = (tau >= 0.0f) ? t : -t;
        float c = __builtin_amdgcn_rsqf(fmaf(t, t, 1.0f));
        float s = t * c;
        #pragma unroll
        for (int k = 0; k < DIM; ++k) o[k] = fmaf(c, o[k], -s * r[k]);
    }
}

// 8 lanes per element: lane h owns G column h.
__global__ void __launch_bounds__(256, 2)
qcbow_kernel(const int* __restrict__ contexts,  // [NB, SEQ]
             const int* __restrict__ targets,   // [NB]
             const float* __restrict__ emb,     // [100000, TRIL]
             float* __restrict__ out)           // [NB]
{
    const int tid = blockIdx.x * 256 + threadIdx.x;
    const int b = tid >> 3;
    const int h = threadIdx.x & 7;

    // ---- token assignment: lane h -> ctx s=h; lanes 0,1 also ctx s=8,9; lanes 4-7 also sigma
    const int base = b * SEQ;
    int tok1 = contexts[base + h];
    int tok2 = 0;                               // lanes 2,3: dummy row 0 (valid memory)
    if (h < 2)  tok2 = contexts[base + 8 + h];
    if (h >= 4) tok2 = targets[b];

    float F1[TRIL], F2[TRIL];                   // both rows loaded up-front (latency overlap)
    load_row(emb, tok1, F1);
    load_row(emb, tok2, F2);

    double A[TRIL];
    #pragma unroll
    for (int i = 0; i < TRIL; ++i) A[i] = 0.0;
    float cntf = 0.0f;

    if (tok1 != 0) { density_from<true>(F1, A); cntf = 1.0f; }
    double T[TRIL];                             // sigma on lanes 4-7; extra-ctx on lanes 0,1
    density_from<false>(F2, T);
    if (h < 2 && tok2 != 0) {
        #pragma unroll
        for (int i = 0; i < TRIL; ++i) A[i] += T[i];
        cntf += 1.0f;
    }

    // ---- allreduce A,cnt over octet: DPP xor1, xor2 + swizzle xor4 ----
    #pragma unroll
    for (int i = 0; i < TRIL; ++i) A[i] += dperm<0xB1>(A[i]);
    cntf += fperm<0xB1>(cntf);
    #pragma unroll
    for (int i = 0; i < TRIL; ++i) A[i] += dperm<0x4E>(A[i]);
    cntf += fperm<0x4E>(cntf);
    #pragma unroll
    for (int i = 0; i < TRIL; ++i) A[i] += dswz4(A[i]);
    cntf += fswz4(cntf);

    double invc = fast_rcp((double)cntf);
    #pragma unroll
    for (int i = 0; i < TRIL; ++i) A[i] *= invc;
    #pragma unroll
    for (int d = 0; d < DIM; ++d) A[tri(d, d)] += 1.0e-6;   // rho_ctx + eps I = sqrt_rho^2

    // ---- ONE chol per lane: quad0 chols rho_ctx, quad1 chols sigma; then exchange ----
    const bool q0 = (h < 4);
    double M[TRIL];
    #pragma unroll
    for (int i = 0; i < TRIL; ++i) M[i] = q0 ? A[i] : T[i];
    chol36(M);

    double Rm[TRIL];                            // partner quad's factor
    #pragma unroll
    for (int i = 0; i < TRIL; ++i) Rm[i] = dswz4(M[i]);

    // Lw (= chol(sigma)) lives in Rm for quad0, M for quad1; pick column j=h via 3-level mux.
    double Lw_[TRIL];
    #pragma unroll
    for (int i = 0; i < TRIL; ++i) Lw_[i] = q0 ? Rm[i] : M[i];
    const bool h1 = (h & 1), h2 = (h & 2), h4 = (h & 4);
    double w[DIM];
    #pragma unroll
    for (int k = 0; k < DIM; ++k) {
        // E(j) = (k>=j) ? Lw_[tri(k,j)] : 0  -- folds at compile time per (k,j)
        #define E(J) ((k >= (J)) ? Lw_[tri((k >= (J)) ? k : (J), (J))] : 0.0)
        double m0 = h1 ? E(1) : E(0);
        double m1 = h1 ? E(3) : E(2);
        double m2 = h1 ? E(5) : E(4);
        double m3 = h1 ? E(7) : E(6);
        #undef E
        double n0 = h2 ? m1 : m0;
        double n1 = h2 ? m3 : m2;
        w[k] = h4 ? n1 : n0;
    }

    // G[:,h] = Lc^T * Lw[:,h]; Lc = chol(rho_ctx+epsI) in M (quad0) / Rm (quad1).
    // eig((rho+epsI) sigma) = eig(G G^T) = squared column norms after one-sided Jacobi.
    float col[DIM];
    #pragma unroll
    for (int i = 0; i < DIM; ++i) {
        double s = 0.0;
        #pragma unroll
        for (int k = i; k < DIM; ++k) {
            double lc = q0 ? M[tri(k, i)] : Rm[tri(k, i)];
            s += lc * w[k];                     // w[k]=0 for k<h handles the W triangle
        }
        col[i] = (float)s;
    }

    // ---- 8-processor one-sided Jacobi, XOR pairing: 7 rounds/sweep cover all 28 pairs ----
    for (int sweep = 0; sweep < 8; ++sweep) {
        bool conv = true;
        jround<1>(col, conv);
        jround<2>(col, conv);
        jround<3>(col, conv);
        jround<4>(col, conv);
        jround<5>(col, conv);
        jround<6>(col, conv);
        jround<7>(col, conv);
        if (sweep >= 2 && __all(conv)) break;   // wave-uniform exit
    }

    // ---- lambda_h = ||col||^2 ; f = sum_h sqrt(lambda+1e-6) over octet ----
    double xn = 0.0;
    #pragma unroll
    for (int k = 0; k < DIM; ++k) xn += (double)col[k] * (double)col[k];
    double fp = fast_sqrt(xn + 1.0e-6);
    fp += dperm<0xB1>(fp);
    fp += dperm<0x4E>(fp);
    fp += dswz4(fp);
    if (h == 0) {
        double f = fmin(fp, 1.0);
        f = fmax(f, 1.0e-8);
        out[b] = (float)(-log(f));
    }
}

extern "C" void kernel_launch(void* const* d_in, const int* in_sizes, int n_in,
                              void* d_out, int out_size, void* d_ws, size_t ws_size,
                              hipStream_t stream) {
    const int*   contexts = (const int*)d_in[0];
    const int*   targets  = (const int*)d_in[1];
    const float* emb      = (const float*)d_in[2];
    float*       out      = (float*)d_out;

    qcbow_kernel<<<dim3(NB * 8 / 256), dim3(256), 0, stream>>>(contexts, targets, emb, out);
}